// Round 1
// baseline (1558.076 us; speedup 1.0000x reference)
//
#include <hip/hip_runtime.h>
#include <hip/hip_bf16.h>
#include <math.h>

#define N_NODES 50000
#define N_EDGES 800000
#define IN_F    128
#define HID_F   128
#define OUT_F   64
#define NLAYERS 8
#define ALPHA_C 0.1f
#define BN_EPS  1e-5f

// ---------------------------------------------------------------------------
// CSR build: degree count -> scan -> scatter
// ---------------------------------------------------------------------------

__global__ __launch_bounds__(256) void k_init(int* cnt, int* fill, float* stats) {
    int i = blockIdx.x * 256 + threadIdx.x;
    if (i < N_NODES) { cnt[i] = 0; fill[i] = 0; }
    if (i < 256) stats[i] = 0.0f;
}

__global__ __launch_bounds__(256) void k_count(const int* __restrict__ dst, int* cnt) {
    int e = blockIdx.x * 256 + threadIdx.x;
    if (e < N_EDGES) atomicAdd(&cnt[dst[e]], 1);
}

__global__ __launch_bounds__(256) void k_dinv(const int* __restrict__ cnt, float* __restrict__ dinv) {
    int i = blockIdx.x * 256 + threadIdx.x;
    if (i < N_NODES) dinv[i] = rsqrtf((float)(cnt[i] + 1));  // +1 self-loop
}

// single-block scan over 50000 ints (exclusive prefix -> rowptr, rowptr[N]=E)
__global__ __launch_bounds__(1024) void k_scan(const int* __restrict__ cnt, int* __restrict__ rowptr) {
    __shared__ int tmp[1024];
    __shared__ int carry;
    int t = threadIdx.x;
    if (t == 0) carry = 0;
    __syncthreads();
    for (int base = 0; base < N_NODES; base += 1024) {
        int i = base + t;
        int v = (i < N_NODES) ? cnt[i] : 0;
        tmp[t] = v;
        __syncthreads();
        for (int off = 1; off < 1024; off <<= 1) {
            int y = (t >= off) ? tmp[t - off] : 0;
            __syncthreads();
            tmp[t] += y;
            __syncthreads();
        }
        int incl = tmp[t];
        int c = carry;
        if (i < N_NODES) rowptr[i] = c + incl - v;
        int total = tmp[1023];
        __syncthreads();
        if (t == 0) carry = c + total;
        __syncthreads();
    }
    if (t == 0) rowptr[N_NODES] = carry;
}

__global__ __launch_bounds__(256) void k_scatter(const int* __restrict__ src, const int* __restrict__ dst,
                                                 const int* __restrict__ rowptr, int* fill,
                                                 const float* __restrict__ dinv,
                                                 int* __restrict__ ssrc, float* __restrict__ snorm) {
    int e = blockIdx.x * 256 + threadIdx.x;
    if (e < N_EDGES) {
        int s = src[e], d = dst[e];
        int pos = rowptr[d] + atomicAdd(&fill[d], 1);
        ssrc[pos] = s;
        snorm[pos] = dinv[s] * dinv[d];
    }
}

// ---------------------------------------------------------------------------
// GEMM: C[M x TJ] = A[M x 128] @ B', tiled 64 rows x TJ cols per block.
// TRANSB: B is [TJ,128] row-major (use B^T)  else B is [128,TJ] k-major.
// MODE 0: C = relu(A@B' + bias), also write C2 (h and h0)
// MODE 1: C = (1-beta)*A + beta*(A@B')   (in-place safe, C may alias A)
// MODE 2: C = A@B' + bias
// ---------------------------------------------------------------------------
template<int TJ, bool TRANSB, int MODE>
__global__ __launch_bounds__(256) void k_gemm(const float* __restrict__ A, const float* __restrict__ B,
                                              const float* __restrict__ bias, float* __restrict__ C,
                                              float* __restrict__ C2, float beta_c, int M) {
    constexpr int CPT = TJ / 16;       // cols per thread: 8 (TJ=128) or 4 (TJ=64)
    constexpr int QN  = CPT / 4;       // float4 groups per thread: 2 or 1
    __shared__ float Ast[16][68];      // A-tile transposed [kk][row], padded
    __shared__ float Bs[16][TJ];       // B-tile [kk][col]

    int tid = threadIdx.x;
    int tx = tid & 15;                 // col group
    int ty = tid >> 4;                 // row group (0..15), rows ty*4..ty*4+3
    int n0 = blockIdx.x * 64;

    float4 acc[4][QN];
#pragma unroll
    for (int i = 0; i < 4; ++i)
#pragma unroll
        for (int q = 0; q < QN; ++q) acc[i][q] = make_float4(0.f, 0.f, 0.f, 0.f);

    for (int k0 = 0; k0 < 128; k0 += 16) {
        // stage A (transposed): thread t covers (row=t>>2, k=k0+4(t&3)..+3)
        {
            int r = tid >> 2, q = tid & 3;
            int row = n0 + r;
            float4 v = make_float4(0.f, 0.f, 0.f, 0.f);
            if (row < M) v = *(const float4*)(A + (size_t)row * 128 + k0 + q * 4);
            Ast[q * 4 + 0][r] = v.x;
            Ast[q * 4 + 1][r] = v.y;
            Ast[q * 4 + 2][r] = v.z;
            Ast[q * 4 + 3][r] = v.w;
        }
        // stage B
        if (TRANSB) {
            int j = tid >> 2, q = tid & 3;
#pragma unroll
            for (int rep = 0; rep < TJ / 64; ++rep) {
                int jj = j + rep * 64;
                float4 v = *(const float4*)(B + (size_t)jj * 128 + k0 + q * 4);
                Bs[q * 4 + 0][jj] = v.x;
                Bs[q * 4 + 1][jj] = v.y;
                Bs[q * 4 + 2][jj] = v.z;
                Bs[q * 4 + 3][jj] = v.w;
            }
        } else {
            int kk = tid >> 4, c4 = (tid & 15) * 4;
#pragma unroll
            for (int q = 0; q < QN; ++q) {
                float4 v = *(const float4*)(B + (size_t)(k0 + kk) * 128 + c4 + q * 64);
                *(float4*)(&Bs[kk][c4 + q * 64]) = v;
            }
        }
        __syncthreads();

#pragma unroll
        for (int kk = 0; kk < 16; ++kk) {
            float4 av = *(const float4*)(&Ast[kk][ty * 4]);
            float a[4] = {av.x, av.y, av.z, av.w};
#pragma unroll
            for (int q = 0; q < QN; ++q) {
                float4 bv = *(const float4*)(&Bs[kk][tx * 4 + q * 64]);
#pragma unroll
                for (int i = 0; i < 4; ++i) {
                    acc[i][q].x = fmaf(a[i], bv.x, acc[i][q].x);
                    acc[i][q].y = fmaf(a[i], bv.y, acc[i][q].y);
                    acc[i][q].z = fmaf(a[i], bv.z, acc[i][q].z);
                    acc[i][q].w = fmaf(a[i], bv.w, acc[i][q].w);
                }
            }
        }
        __syncthreads();
    }

    // epilogue: thread's cols are j = tx*4 + q*64 + {0..3}
#pragma unroll
    for (int i = 0; i < 4; ++i) {
        int row = n0 + ty * 4 + i;
        if (row >= M) continue;
#pragma unroll
        for (int q = 0; q < QN; ++q) {
            int j4 = tx * 4 + q * 64;
            float4 v = acc[i][q];
            if (MODE == 0) {
                float4 b = *(const float4*)(bias + j4);
                v.x = fmaxf(v.x + b.x, 0.f); v.y = fmaxf(v.y + b.y, 0.f);
                v.z = fmaxf(v.z + b.z, 0.f); v.w = fmaxf(v.w + b.w, 0.f);
                *(float4*)(C + (size_t)row * TJ + j4) = v;
                *(float4*)(C2 + (size_t)row * TJ + j4) = v;
            } else if (MODE == 1) {
                float4 z = *(const float4*)(A + (size_t)row * 128 + j4);
                float ob = 1.0f - beta_c;
                v.x = ob * z.x + beta_c * v.x; v.y = ob * z.y + beta_c * v.y;
                v.z = ob * z.z + beta_c * v.z; v.w = ob * z.w + beta_c * v.w;
                *(float4*)(C + (size_t)row * 128 + j4) = v;
            } else {
                float4 b = *(const float4*)(bias + j4);
                v.x += b.x; v.y += b.y; v.z += b.z; v.w += b.w;
                *(float4*)(C + (size_t)row * TJ + j4) = v;
            }
        }
    }
}

// ---------------------------------------------------------------------------
// Sparse aggregation + residual: Z[v,:] = 0.9*(sum_e norm*h[src] + dinv[v]^2*h[v]) + 0.1*h0[v,:]
// one wave per dst row, lane l owns features {2l, 2l+1}
// ---------------------------------------------------------------------------
__global__ __launch_bounds__(256) void k_aggregate(const float* __restrict__ h, const float* __restrict__ h0,
                                                   const int* __restrict__ rowptr, const int* __restrict__ ssrc,
                                                   const float* __restrict__ snorm, const float* __restrict__ dinv,
                                                   float* __restrict__ Z) {
    int wave = threadIdx.x >> 6;
    int lane = threadIdx.x & 63;
    int v = blockIdx.x * 4 + wave;
    if (v >= N_NODES) return;
    int beg = rowptr[v], end = rowptr[v + 1];
    float dv = dinv[v];
    float2 acc;
    {
        float2 hv = ((const float2*)(h + (size_t)v * 128))[lane];
        float w = dv * dv;
        acc.x = w * hv.x; acc.y = w * hv.y;
    }
    for (int p = beg; p < end; ++p) {
        int s = ssrc[p];
        float w = snorm[p];
        float2 hv = ((const float2*)(h + (size_t)s * 128))[lane];
        acc.x = fmaf(w, hv.x, acc.x);
        acc.y = fmaf(w, hv.y, acc.y);
    }
    float2 prev = ((const float2*)(h0 + (size_t)v * 128))[lane];
    float2 z;
    z.x = (1.0f - ALPHA_C) * acc.x + ALPHA_C * prev.x;
    z.y = (1.0f - ALPHA_C) * acc.y + ALPHA_C * prev.y;
    ((float2*)(Z + (size_t)v * 128))[lane] = z;
}

// ---------------------------------------------------------------------------
// BatchNorm: per-feature sum/sumsq -> finalize -> scale/shift + relu
// ---------------------------------------------------------------------------
__global__ __launch_bounds__(256) void k_stats(const float* __restrict__ Z, float* __restrict__ stats) {
    int j = threadIdx.x & 127;
    int half = threadIdx.x >> 7;
    float s = 0.f, ss = 0.f;
    for (int r = blockIdx.x * 2 + half; r < N_NODES; r += gridDim.x * 2) {
        float v = Z[(size_t)r * 128 + j];
        s += v;
        ss = fmaf(v, v, ss);
    }
    __shared__ float red[256];
    red[threadIdx.x] = s;
    __syncthreads();
    if (half == 0) atomicAdd(&stats[j], s + red[threadIdx.x + 128]);
    __syncthreads();
    red[threadIdx.x] = ss;
    __syncthreads();
    if (half == 0) atomicAdd(&stats[128 + j], ss + red[threadIdx.x + 128]);
}

__global__ void k_bn_finalize(float* stats, const float* __restrict__ gamma, const float* __restrict__ betap,
                              float* __restrict__ scsh) {
    int j = threadIdx.x;  // 128 threads
    float mean = stats[j] * (1.0f / N_NODES);
    float var = stats[128 + j] * (1.0f / N_NODES) - mean * mean;
    float istd = rsqrtf(var + BN_EPS);
    float sc = gamma[j] * istd;
    scsh[j] = sc;
    scsh[128 + j] = betap[j] - mean * sc;
    // re-zero for next layer
    stats[j] = 0.f;
    stats[128 + j] = 0.f;
}

__global__ __launch_bounds__(256) void k_bn_relu(const float* __restrict__ Z, const float* __restrict__ scsh,
                                                 float* __restrict__ h) {
    size_t i = ((size_t)blockIdx.x * 256 + threadIdx.x) * 4;  // exact: N*128 = 6.4M
    int j = (int)(i & 127);
    float4 z = *(const float4*)(Z + i);
    float4 r;
    r.x = fmaxf(fmaf(z.x, scsh[j + 0], scsh[128 + j + 0]), 0.f);
    r.y = fmaxf(fmaf(z.y, scsh[j + 1], scsh[128 + j + 1]), 0.f);
    r.z = fmaxf(fmaf(z.z, scsh[j + 2], scsh[128 + j + 2]), 0.f);
    r.w = fmaxf(fmaf(z.w, scsh[j + 3], scsh[128 + j + 3]), 0.f);
    *(float4*)(h + i) = r;
}

// ---------------------------------------------------------------------------

extern "C" void kernel_launch(void* const* d_in, const int* in_sizes, int n_in,
                              void* d_out, int out_size, void* d_ws, size_t ws_size,
                              hipStream_t stream) {
    const float* x      = (const float*)d_in[0];
    const int*   ei     = (const int*)d_in[1];
    const float* lin0_w = (const float*)d_in[2];
    const float* lin0_b = (const float*)d_in[3];
    const float* lin1_w = (const float*)d_in[4];
    const float* lin1_b = (const float*)d_in[5];
    const float* conv_w = (const float*)d_in[6];
    const float* bn_g   = (const float*)d_in[7];
    const float* bn_b   = (const float*)d_in[8];
    const int* e_src = ei;
    const int* e_dst = ei + N_EDGES;

    // workspace carve (~84 MB total)
    char* p = (char*)d_ws;
    auto alloc = [&](size_t bytes) -> void* {
        void* r = (void*)p;
        p += (bytes + 255) & ~(size_t)255;
        return r;
    };
    int*   cnt    = (int*)alloc((size_t)N_NODES * 4);
    int*   rowptr = (int*)alloc((size_t)(N_NODES + 1) * 4);
    int*   fill   = (int*)alloc((size_t)N_NODES * 4);
    float* dinv   = (float*)alloc((size_t)N_NODES * 4);
    int*   ssrc   = (int*)alloc((size_t)N_EDGES * 4);
    float* snorm  = (float*)alloc((size_t)N_EDGES * 4);
    float* h      = (float*)alloc((size_t)N_NODES * HID_F * 4);
    float* h0     = (float*)alloc((size_t)N_NODES * HID_F * 4);
    float* Z      = (float*)alloc((size_t)N_NODES * HID_F * 4);
    float* stats  = (float*)alloc(256 * 4);
    float* scsh   = (float*)alloc(256 * 4);

    const int nblk = (N_NODES + 255) / 256;
    const int eblk = (N_EDGES + 255) / 256;
    const int gblk = (N_NODES + 63) / 64;

    // graph normalization + CSR build
    k_init<<<nblk, 256, 0, stream>>>(cnt, fill, stats);
    k_count<<<eblk, 256, 0, stream>>>(e_dst, cnt);
    k_dinv<<<nblk, 256, 0, stream>>>(cnt, dinv);
    k_scan<<<1, 1024, 0, stream>>>(cnt, rowptr);
    k_scatter<<<eblk, 256, 0, stream>>>(e_src, e_dst, rowptr, fill, dinv, ssrc, snorm);

    // input projection: h = h0 = relu(x @ lin0_w.T + lin0_b)
    k_gemm<128, true, 0><<<gblk, 256, 0, stream>>>(x, lin0_w, lin0_b, h, h0, 0.f, N_NODES);

    for (int i = 0; i < NLAYERS; ++i) {
        k_aggregate<<<(N_NODES + 3) / 4, 256, 0, stream>>>(h, h0, rowptr, ssrc, snorm, dinv, Z);
        float beta = (float)log(0.5 / (double)(i + 1) + 1.0);
        k_gemm<128, false, 1><<<gblk, 256, 0, stream>>>(Z, conv_w + (size_t)i * 128 * 128, nullptr, Z, nullptr, beta, N_NODES);
        k_stats<<<256, 256, 0, stream>>>(Z, stats);
        k_bn_finalize<<<1, 128, 0, stream>>>(stats, bn_g + i * 128, bn_b + i * 128, scsh);
        k_bn_relu<<<(N_NODES * HID_F / 4 + 255) / 256, 256, 0, stream>>>(Z, scsh, h);
    }

    // output projection
    k_gemm<64, true, 2><<<gblk, 256, 0, stream>>>(h, lin1_w, lin1_b, (float*)d_out, nullptr, 0.f, N_NODES);
}

// Round 2
// 1288.584 us; speedup vs baseline: 1.2091x; 1.2091x over previous
//
#include <hip/hip_runtime.h>
#include <hip/hip_bf16.h>
#include <math.h>

#define N_NODES 50000
#define N_EDGES 800000
#define NLAYERS 8
#define ALPHA_C 0.1f
#define BN_EPS  1e-5f

typedef unsigned short u16;
typedef __attribute__((ext_vector_type(8))) short short8;
typedef __attribute__((ext_vector_type(4))) float f32x4;

static __device__ __forceinline__ u16 f2bf(float f) {
    unsigned u = __float_as_uint(f);
    unsigned r = (u + 0x7fffu + ((u >> 16) & 1u)) >> 16;
    return (u16)r;
}
static __device__ __forceinline__ float bf2f(u16 b) {
    return __uint_as_float((unsigned)b << 16);
}

// ---------------------------------------------------------------------------
// CSR build
// ---------------------------------------------------------------------------
__global__ __launch_bounds__(256) void k_init(int* cnt, int* fill, float* stats) {
    int i = blockIdx.x * 256 + threadIdx.x;
    if (i < N_NODES) { cnt[i] = 0; fill[i] = 0; }
    if (i < 256) stats[i] = 0.0f;
}

__global__ __launch_bounds__(256) void k_count(const int* __restrict__ dst, int* cnt) {
    int e = blockIdx.x * 256 + threadIdx.x;
    if (e < N_EDGES) atomicAdd(&cnt[dst[e]], 1);
}

__global__ __launch_bounds__(256) void k_dinv(const int* __restrict__ cnt, float* __restrict__ dinv) {
    int i = blockIdx.x * 256 + threadIdx.x;
    if (i < N_NODES) dinv[i] = rsqrtf((float)(cnt[i] + 1));  // +1 self-loop
}

__global__ __launch_bounds__(1024) void k_scan(const int* __restrict__ cnt, int* __restrict__ rowptr) {
    __shared__ int tmp[1024];
    __shared__ int carry;
    int t = threadIdx.x;
    if (t == 0) carry = 0;
    __syncthreads();
    for (int base = 0; base < N_NODES; base += 1024) {
        int i = base + t;
        int v = (i < N_NODES) ? cnt[i] : 0;
        tmp[t] = v;
        __syncthreads();
        for (int off = 1; off < 1024; off <<= 1) {
            int y = (t >= off) ? tmp[t - off] : 0;
            __syncthreads();
            tmp[t] += y;
            __syncthreads();
        }
        int incl = tmp[t];
        int c = carry;
        if (i < N_NODES) rowptr[i] = c + incl - v;
        int total = tmp[1023];
        __syncthreads();
        if (t == 0) carry = c + total;
        __syncthreads();
    }
    if (t == 0) rowptr[N_NODES] = carry;
}

__global__ __launch_bounds__(256) void k_scatter(const int* __restrict__ src, const int* __restrict__ dst,
                                                 const int* __restrict__ rowptr, int* fill,
                                                 const float* __restrict__ dinv,
                                                 int2* __restrict__ edges) {
    int e = blockIdx.x * 256 + threadIdx.x;
    if (e < N_EDGES) {
        int s = src[e], d = dst[e];
        int pos = rowptr[d] + atomicAdd(&fill[d], 1);
        edges[pos] = make_int2(s, __float_as_int(dinv[s] * dinv[d]));
    }
}

// ---------------------------------------------------------------------------
// Weight convert: fp32 -> bf16, transposed to [j][k], XOR-swizzled (elem idx
// k' = k ^ ((j&7)<<3), i.e. byte ^ ((j&7)<<4)) so LDS ds_read_b128 of 8
// contiguous k per lane is bank-conflict-free.
// layout in wtb (elements): conv layer i at i*16384, lin0 at 131072, lin1 at 147456
// ---------------------------------------------------------------------------
__global__ __launch_bounds__(256) void k_convw(const float* __restrict__ conv_w,
                                               const float* __restrict__ lin0_w,
                                               const float* __restrict__ lin1_w,
                                               u16* __restrict__ wtb) {
    int t = blockIdx.x * 256 + threadIdx.x;
    if (t < 131072) {                       // conv: need W^T: B[j][k] = conv_w[i][k][j]
        int j = (t >> 7) & 127, k = t & 127;
        int i = t >> 14;
        float v = conv_w[(i << 14) + (k << 7) + j];
        wtb[(t & ~127) | (k ^ ((j & 7) << 3))] = f2bf(v);
    } else if (t < 131072 + 16384) {        // lin0_w [128][128] already [j][k]
        int u = t - 131072;
        int j = u >> 7, k = u & 127;
        wtb[131072 + ((u & ~127) | (k ^ ((j & 7) << 3)))] = f2bf(lin0_w[u]);
    } else if (t < 131072 + 16384 + 8192) { // lin1_w [64][128] already [j][k]
        int u = t - 147456;
        int j = u >> 7, k = u & 127;
        wtb[147456 + ((u & ~127) | (k ^ ((j & 7) << 3)))] = f2bf(lin1_w[u]);
    }
}

__global__ __launch_bounds__(256) void k_convx(const float* __restrict__ x, u16* __restrict__ xb) {
    size_t i = ((size_t)blockIdx.x * 256 + threadIdx.x) * 4;  // N*128 divisible by 4
    float4 v = *(const float4*)(x + i);
    uint2 o;
    o.x = (unsigned)f2bf(v.x) | ((unsigned)f2bf(v.y) << 16);
    o.y = (unsigned)f2bf(v.z) | ((unsigned)f2bf(v.w) << 16);
    *(uint2*)(xb + i) = o;
}

// ---------------------------------------------------------------------------
// MFMA GEMM: C[M x NT*16] = A[M x 128](bf16) @ W'(bf16, [j][k] swizzled)
// 256 threads = 4 waves, 64 rows/block (16 rows/wave), full K=128.
// mfma_f32_16x16x32_bf16: A-frag lane l: row=l&15, k=8*(l>>4)+e
//                         B-frag lane l: col=l&15, k=8*(l>>4)+e
//                         D:      lane l: col=l&15, row=4*(l>>4)+reg   [m89]
// MODE 0: v=relu(acc+bias); Cout(h0,f32)=v; Cbf(hb,bf16)=v
// MODE 1: v=(1-beta)*Zin + beta*acc; Cout=v (may alias Zin); BN stats atomics
// MODE 2: Cout = acc + bias   (stride NT*16)
// ---------------------------------------------------------------------------
template<int NT, int MODE>
__global__ __launch_bounds__(256) void k_gemm_mfma(const u16* __restrict__ A,
                                                   const u16* __restrict__ Wg,
                                                   const float* __restrict__ bias,
                                                   const float* __restrict__ Zin,
                                                   float* __restrict__ Cout,
                                                   u16* __restrict__ Cbf,
                                                   float* __restrict__ stats,
                                                   float beta_c, int M) {
    __shared__ u16 Ws[NT * 16 * 128];
    __shared__ float sstat[256];
    int tid = threadIdx.x;

    // stage W (pre-swizzled in global -> plain linear copy)
    {
        const float4* srcv = (const float4*)Wg;
        float4* dstv = (float4*)Ws;
#pragma unroll
        for (int i = 0; i < NT; ++i) dstv[tid + i * 256] = srcv[tid + i * 256];
    }
    if (MODE == 1) sstat[tid] = 0.f;

    int wave = tid >> 6, lane = tid & 63;
    int r0 = blockIdx.x * 64 + wave * 16;
    int kg = lane >> 4;            // k-group 0..3
    int cl = lane & 15;

    int arow = r0 + cl;
    int acl = arow < M ? arow : M - 1;
    short8 afrag[4];
#pragma unroll
    for (int kk = 0; kk < 4; ++kk)
        afrag[kk] = *(const short8*)(A + (size_t)acl * 128 + kk * 32 + kg * 8);

    __syncthreads();

    f32x4 acc[NT];
#pragma unroll
    for (int nt = 0; nt < NT; ++nt) {
        acc[nt] = (f32x4){0.f, 0.f, 0.f, 0.f};
        int j = nt * 16 + cl;
        const u16* wrow = Ws + j * 128;
        int sw = (j & 7) << 3;
#pragma unroll
        for (int kk = 0; kk < 4; ++kk) {
            short8 b = *(const short8*)(wrow + ((kk * 32 + kg * 8) ^ sw));
            acc[nt] = __builtin_amdgcn_mfma_f32_16x16x32_bf16(afrag[kk], b, acc[nt], 0, 0, 0);
        }
    }

    // epilogue: D row = r0 + kg*4 + reg, col j = nt*16 + cl
    int rbase = r0 + kg * 4;
#pragma unroll
    for (int nt = 0; nt < NT; ++nt) {
        int j = nt * 16 + cl;
        float s = 0.f, ss = 0.f;
#pragma unroll
        for (int reg = 0; reg < 4; ++reg) {
            int row = rbase + reg;
            if (row >= M) continue;
            float v = acc[nt][reg];
            if (MODE == 0) {
                v = fmaxf(v + bias[j], 0.f);
                Cout[(size_t)row * 128 + j] = v;
                Cbf[(size_t)row * 128 + j] = f2bf(v);
            } else if (MODE == 1) {
                float zin = Zin[(size_t)row * 128 + j];
                v = (1.0f - beta_c) * zin + beta_c * v;
                Cout[(size_t)row * 128 + j] = v;
                s += v;
                ss = fmaf(v, v, ss);
            } else {
                Cout[(size_t)row * (NT * 16) + j] = v + bias[j];
            }
        }
        if (MODE == 1) {
            s  += __shfl_xor(s, 16);  s  += __shfl_xor(s, 32);
            ss += __shfl_xor(ss, 16); ss += __shfl_xor(ss, 32);
            if (kg == 0) {
                atomicAdd(&sstat[j], s);
                atomicAdd(&sstat[128 + j], ss);
            }
        }
    }
    if (MODE == 1) {
        __syncthreads();
        atomicAdd(&stats[tid], sstat[tid]);
    }
}

// ---------------------------------------------------------------------------
// Sparse aggregation: Z[v,:] = 0.9*(sum_e norm*hb[src] + dinv^2*hb[v]) + 0.1*h0[v,:]
// one wave per dst row; lane owns feats {2l,2l+1}; writes Z fp32 + Zb bf16
// ---------------------------------------------------------------------------
__global__ __launch_bounds__(256) void k_aggregate(const u16* __restrict__ hb, const float* __restrict__ h0,
                                                   const int* __restrict__ rowptr, const int2* __restrict__ edges,
                                                   const float* __restrict__ dinv,
                                                   float* __restrict__ Z, u16* __restrict__ Zb) {
    int wave = threadIdx.x >> 6;
    int lane = threadIdx.x & 63;
    int v = blockIdx.x * 4 + wave;
    if (v >= N_NODES) return;
    int beg = rowptr[v], end = rowptr[v + 1];
    float dv = dinv[v];
    float2 acc;
    {
        unsigned u = *(const unsigned*)(hb + (size_t)v * 128 + lane * 2);
        float w = dv * dv;
        acc.x = w * bf2f((u16)(u & 0xffff));
        acc.y = w * bf2f((u16)(u >> 16));
    }
    for (int p = beg; p < end; ++p) {
        int2 e = edges[p];
        float w = __int_as_float(e.y);
        unsigned u = *(const unsigned*)(hb + (size_t)e.x * 128 + lane * 2);
        acc.x = fmaf(w, bf2f((u16)(u & 0xffff)), acc.x);
        acc.y = fmaf(w, bf2f((u16)(u >> 16)), acc.y);
    }
    float2 prev = ((const float2*)(h0 + (size_t)v * 128))[lane];
    float2 z;
    z.x = (1.0f - ALPHA_C) * acc.x + ALPHA_C * prev.x;
    z.y = (1.0f - ALPHA_C) * acc.y + ALPHA_C * prev.y;
    ((float2*)(Z + (size_t)v * 128))[lane] = z;
    *(unsigned*)(Zb + (size_t)v * 128 + lane * 2) =
        (unsigned)f2bf(z.x) | ((unsigned)f2bf(z.y) << 16);
}

// ---------------------------------------------------------------------------
// BN finalize + apply
// ---------------------------------------------------------------------------
__global__ void k_bn_finalize(float* stats, const float* __restrict__ gamma, const float* __restrict__ betap,
                              float* __restrict__ scsh) {
    int j = threadIdx.x;  // 128
    float mean = stats[j] * (1.0f / N_NODES);
    float var = stats[128 + j] * (1.0f / N_NODES) - mean * mean;
    float istd = rsqrtf(var + BN_EPS);
    float sc = gamma[j] * istd;
    scsh[j] = sc;
    scsh[128 + j] = betap[j] - mean * sc;
    stats[j] = 0.f;
    stats[128 + j] = 0.f;
}

__global__ __launch_bounds__(256) void k_bn_relu(const float* __restrict__ Z, const float* __restrict__ scsh,
                                                 u16* __restrict__ hb) {
    size_t i = ((size_t)blockIdx.x * 256 + threadIdx.x) * 4;
    int j = (int)(i & 127);
    float4 z = *(const float4*)(Z + i);
    float4 r;
    r.x = fmaxf(fmaf(z.x, scsh[j + 0], scsh[128 + j + 0]), 0.f);
    r.y = fmaxf(fmaf(z.y, scsh[j + 1], scsh[128 + j + 1]), 0.f);
    r.z = fmaxf(fmaf(z.z, scsh[j + 2], scsh[128 + j + 2]), 0.f);
    r.w = fmaxf(fmaf(z.w, scsh[j + 3], scsh[128 + j + 3]), 0.f);
    uint2 o;
    o.x = (unsigned)f2bf(r.x) | ((unsigned)f2bf(r.y) << 16);
    o.y = (unsigned)f2bf(r.z) | ((unsigned)f2bf(r.w) << 16);
    *(uint2*)(hb + i) = o;
}

// ---------------------------------------------------------------------------

extern "C" void kernel_launch(void* const* d_in, const int* in_sizes, int n_in,
                              void* d_out, int out_size, void* d_ws, size_t ws_size,
                              hipStream_t stream) {
    const float* x      = (const float*)d_in[0];
    const int*   ei     = (const int*)d_in[1];
    const float* lin0_w = (const float*)d_in[2];
    const float* lin0_b = (const float*)d_in[3];
    const float* lin1_w = (const float*)d_in[4];
    const float* lin1_b = (const float*)d_in[5];
    const float* conv_w = (const float*)d_in[6];
    const float* bn_g   = (const float*)d_in[7];
    const float* bn_b   = (const float*)d_in[8];
    const int* e_src = ei;
    const int* e_dst = ei + N_EDGES;

    char* p = (char*)d_ws;
    auto alloc = [&](size_t bytes) -> void* {
        void* r = (void*)p;
        p += (bytes + 255) & ~(size_t)255;
        return r;
    };
    int*   cnt    = (int*)alloc((size_t)N_NODES * 4);
    int*   rowptr = (int*)alloc((size_t)(N_NODES + 1) * 4);
    int*   fill   = (int*)alloc((size_t)N_NODES * 4);
    float* dinv   = (float*)alloc((size_t)N_NODES * 4);
    int2*  edges  = (int2*)alloc((size_t)N_EDGES * 8);
    float* h0     = (float*)alloc((size_t)N_NODES * 128 * 4);
    float* Z      = (float*)alloc((size_t)N_NODES * 128 * 4);
    u16*   Zb     = (u16*)alloc((size_t)N_NODES * 128 * 2);   // also xb before layer 0
    u16*   hb     = (u16*)alloc((size_t)N_NODES * 128 * 2);
    u16*   wtb    = (u16*)alloc((size_t)(131072 + 16384 + 8192) * 2);
    float* stats  = (float*)alloc(256 * 4);
    float* scsh   = (float*)alloc(256 * 4);

    const int nblk = (N_NODES + 255) / 256;
    const int eblk = (N_EDGES + 255) / 256;
    const int gblk = (N_NODES + 63) / 64;       // 782
    const int vblk = N_NODES * 128 / 4 / 256;   // 6250

    // CSR + weight prep
    k_init<<<nblk, 256, 0, stream>>>(cnt, fill, stats);
    k_count<<<eblk, 256, 0, stream>>>(e_dst, cnt);
    k_dinv<<<nblk, 256, 0, stream>>>(cnt, dinv);
    k_scan<<<1, 1024, 0, stream>>>(cnt, rowptr);
    k_scatter<<<eblk, 256, 0, stream>>>(e_src, e_dst, rowptr, fill, dinv, edges);
    k_convw<<<(131072 + 16384 + 8192 + 255) / 256, 256, 0, stream>>>(conv_w, lin0_w, lin1_w, wtb);
    k_convx<<<vblk, 256, 0, stream>>>(x, Zb);

    // input projection: h0(f32) & hb(bf16) = relu(x @ lin0_w.T + b)
    k_gemm_mfma<8, 0><<<gblk, 256, 0, stream>>>(Zb, wtb + 131072, lin0_b, nullptr, h0, hb, nullptr, 0.f, N_NODES);

    for (int i = 0; i < NLAYERS; ++i) {
        k_aggregate<<<(N_NODES + 3) / 4, 256, 0, stream>>>(hb, h0, rowptr, edges, dinv, Z, Zb);
        float beta = (float)log(0.5 / (double)(i + 1) + 1.0);
        k_gemm_mfma<8, 1><<<gblk, 256, 0, stream>>>(Zb, wtb + (size_t)i * 16384, nullptr, Z, Z, nullptr, stats, beta, N_NODES);
        k_bn_finalize<<<1, 128, 0, stream>>>(stats, bn_g + i * 128, bn_b + i * 128, scsh);
        k_bn_relu<<<vblk, 256, 0, stream>>>(Z, scsh, hb);
    }

    // output projection
    k_gemm_mfma<4, 2><<<gblk, 256, 0, stream>>>(hb, wtb + 147456, lin1_b, nullptr, (float*)d_out, nullptr, nullptr, 0.f, N_NODES);
}